// Round 16
// baseline (9006053.906 us; speedup 1.0000x reference)
//
#include <hip/hip_runtime.h>

// LSTM encoder: V=32000 E=512 U=1024 L=2, B=64 T=256.
// Round 16: r15 (XCD-local recurrence) with the flag-region stride bug fixed
// (gArr stride 64 -> 128 lines: r15's release lines clobbered the next
// group's arrive lines -> cross-group circular wait -> 600s timeout).
// Plus: guarded spin loops (deadlock => fast wrong-answer, not timeout) and
// sc0sc1 A1 reads in L1 (replay-staleness safety; off critical path).
// Group (layer,quarter) = 64 blocks with bid%8 == l*4+q -> one XCD
// (runtime-verified via HW_REG_XCC_ID; slow L3 flavor if non-uniform).

typedef _Float16 f16;
typedef _Float16 f16x8 __attribute__((ext_vector_type(8)));
typedef _Float16 f16x4 __attribute__((ext_vector_type(4)));
typedef float f32x4 __attribute__((ext_vector_type(4)));

#define POLL_GUARD(cond)                                     \
  {                                                          \
    unsigned gg_ = 0;                                        \
    while ((cond) && (++gg_ < (1u << 18)))                   \
      __builtin_amdgcn_s_sleep(1);                           \
  }

__device__ __forceinline__ f32x4 mfma16x32(f16x8 a, f16x8 b, f32x4 c) {
  return __builtin_amdgcn_mfma_f32_16x16x32_f16(a, b, c, 0, 0, 0);
}

__device__ __forceinline__ void gl_lds16(const void* g, void* l) {
  __builtin_amdgcn_global_load_lds(
      (const __attribute__((address_space(1))) void*)g,
      (__attribute__((address_space(3))) void*)l, 16, 0, 0);
}

__device__ __forceinline__ float sigmoidf_(float x) {
  return 1.0f / (1.0f + expf(-x));
}

// ---- cross-XCD write-through stores (land at L3, no dirty L2 line) ----
__device__ __forceinline__ void st_f16_sc(f16* p, float v) {
  f16 h = (f16)v;
  unsigned u = (unsigned)__builtin_bit_cast(unsigned short, h);
  asm volatile("global_store_short %0, %1, off sc0 sc1"
               :: "v"(p), "v"(u) : "memory");
}
__device__ __forceinline__ void st_b128_sc(f16* p, f16x8 v) {
  asm volatile("global_store_dwordx4 %0, %1, off sc0 sc1"
               :: "v"(p), "v"(v) : "memory");
}

// ---- L3 (agent) flags: 1-writer/1-reader lines, relaxed ----
__device__ __forceinline__ unsigned ld_flag(const unsigned* p) {
  return __hip_atomic_load(p, __ATOMIC_RELAXED, __HIP_MEMORY_SCOPE_AGENT);
}
__device__ __forceinline__ void st_flag(unsigned* p, unsigned v) {
  __hip_atomic_store(p, v, __ATOMIC_RELAXED, __HIP_MEMORY_SCOPE_AGENT);
}

// ---- protocol-flavored ops: fast = XCD-local (plain store / sc0 load) ----
__device__ __forceinline__ void st_flag2(unsigned* p, unsigned v, bool fast) {
  if (fast)
    asm volatile("global_store_dword %0, %1, off" :: "v"(p), "v"(v)
                 : "memory");
  else
    st_flag(p, v);
}
__device__ __forceinline__ unsigned ld_flag2(const unsigned* p, bool fast) {
  unsigned r;
  if (fast)
    asm volatile("global_load_dword %0, %1, off sc0\n\ts_waitcnt vmcnt(0)"
                 : "=v"(r) : "v"(p) : "memory");
  else
    r = ld_flag(p);
  return r;
}
__device__ __forceinline__ void st_h16(f16* p, f16x8 v, bool fast) {
  if (fast)
    *(f16x8*)p = v;  // plain: write-through L1 -> local L2
  else
    st_b128_sc(p, v);
}
// 8x16B A-fragment load. fast: sc0 (bypass L1, read local L2).
// slow: sc0 sc1 (read L3). Ends with vmcnt(0)+sched_barrier (rule 18).
__device__ __forceinline__ void ld_frag8(const f16* base, bool fast,
                                         f16x8 o[8]) {
#pragma unroll
  for (int kt = 0; kt < 8; ++kt) {
    const f16* p = base + kt * 32;
    if (fast)
      asm volatile("global_load_dwordx4 %0, %1, off sc0"
                   : "=&v"(o[kt]) : "v"(p));
    else
      asm volatile("global_load_dwordx4 %0, %1, off sc0 sc1"
                   : "=&v"(o[kt]) : "v"(p));
  }
  asm volatile("s_waitcnt vmcnt(0)" ::: "memory");
  __builtin_amdgcn_sched_barrier(0);
}

// ---------- transpose + cast: D[n][k] = (f16)S[k][n] ----------
__global__ __launch_bounds__(256) void k_transpose_f16(
    const float* __restrict__ S, f16* __restrict__ D, int K, int N) {
  __shared__ float tile[64][65];
  int nk = K >> 6;
  int k0 = (blockIdx.x % nk) << 6;
  int n0 = (blockIdx.x / nk) << 6;
  int tc = threadIdx.x & 63;
  int tq = threadIdx.x >> 6;
#pragma unroll
  for (int r = 0; r < 16; ++r) {
    int kk = tq * 16 + r;
    tile[kk][tc] = S[(size_t)(k0 + kk) * N + (n0 + tc)];
  }
  __syncthreads();
#pragma unroll
  for (int r = 0; r < 16; ++r) {
    int nn = tq * 16 + r;
    D[(size_t)(n0 + nn) * K + (k0 + tc)] = (f16)tile[tc][nn];
  }
}

// ---------- embedding lookup -> fp16 A0[m][512], row m = t*64 + b ----------
__global__ __launch_bounds__(256) void k_embed_f16(
    const int* __restrict__ tok, const float* __restrict__ emb,
    f16* __restrict__ A0) {
  int i = blockIdx.x * 256 + threadIdx.x;
  int m = i >> 7;
  int e = (i & 127) << 2;
  int t = m >> 6, b = m & 63;
  int tk = tok[b * 256 + t];
  const float4 v = *(const float4*)(emb + (size_t)tk * 512 + e);
  f16x4 o = {(f16)v.x, (f16)v.y, (f16)v.z, (f16)v.w};
  *(f16x4*)(A0 + (size_t)m * 512 + e) = o;
}

// ---------- C[m][n] = (f16)(sum_k A[m][k]*Bt[n][k] + bias[n]) ----------
__global__ __launch_bounds__(256) void k_gemm_f16(
    const f16* __restrict__ A, const f16* __restrict__ Bt,
    const float* __restrict__ bias, f16* __restrict__ C,
    int M, int N, int K) {
  __shared__ f16 sA[2][128 * 32];
  __shared__ f16 sB[2][128 * 32];
  const int tid = threadIdx.x, lane = tid & 63, w = tid >> 6;
  const int mb = M >> 7;
  const int bm = blockIdx.x % mb, bn = blockIdx.x / mb;
  const int am0 = bm << 7, bn0 = bn << 7;
  const int wm = w >> 1, wn = w & 1;
  const int srow = lane >> 2, sch = lane & 3;

  f32x4 acc[4][4] = {};
  const int NT = K >> 5;
  int cur = 0;

  auto stage = [&](int kt, int buf) {
#pragma unroll
    for (int q2 = 0; q2 < 2; ++q2) {
      int q = w * 2 + q2;
      int row = q * 16 + srow;
      const f16* ga = A + (size_t)(am0 + row) * K + kt * 32 + sch * 8;
      const f16* gb = Bt + (size_t)(bn0 + row) * K + kt * 32 + sch * 8;
      gl_lds16(ga, (char*)&sA[buf][0] + q * 1024);
      gl_lds16(gb, (char*)&sB[buf][0] + q * 1024);
    }
  };

  stage(0, 0);
  __syncthreads();
  for (int kt = 0; kt < NT; ++kt) {
    if (kt + 1 < NT) stage(kt + 1, cur ^ 1);
    const f16* pa = &sA[cur][(wm * 64 + (lane & 15)) * 32 + (lane >> 4) * 8];
    const f16* pb = &sB[cur][(wn * 64 + (lane & 15)) * 32 + (lane >> 4) * 8];
    f16x8 av[4], bv[4];
#pragma unroll
    for (int mf = 0; mf < 4; ++mf) av[mf] = *(const f16x8*)(pa + mf * 512);
#pragma unroll
    for (int nf = 0; nf < 4; ++nf) bv[nf] = *(const f16x8*)(pb + nf * 512);
#pragma unroll
    for (int mf = 0; mf < 4; ++mf)
#pragma unroll
      for (int nf = 0; nf < 4; ++nf)
        acc[mf][nf] = mfma16x32(av[mf], bv[nf], acc[mf][nf]);
    __syncthreads();
    cur ^= 1;
  }

#pragma unroll
  for (int mf = 0; mf < 4; ++mf)
#pragma unroll
    for (int nf = 0; nf < 4; ++nf) {
      int col = bn0 + wn * 64 + nf * 16 + (lane & 15);
      float bs = bias[col];
#pragma unroll
      for (int r = 0; r < 4; ++r) {
        int row = am0 + wm * 64 + mf * 16 + (lane >> 4) * 4 + r;
        C[(size_t)row * N + col] = (f16)(acc[mf][nf][r] + bs);
      }
    }
}

// ---------- XCD-local scan ----------
// bid: k0=bid&7 (XCD), cc=bid>>3 (unit chunk 0..63 -> units [cc*16,cc*16+16)
// x 4 gates = 64 cols). l=(k0>>2)&1 (layer), q=k0&3 (batch quarter: rows
// q*16..q*16+16). Group = 64 blocks on one XCD (verified; else slow flavor).
// Flag regions: 128 lines per group (arrive cc, release 64+cc).
__global__ __launch_bounds__(256, 2) void k_scanA(
    const f16* __restrict__ XZ, const f16* __restrict__ U0t,
    const f16* __restrict__ W1t, const f16* __restrict__ U1t,
    const float* __restrict__ b1, f16* __restrict__ A1,
    f16* __restrict__ Hl0, f16* __restrict__ Hl1, float* __restrict__ out,
    unsigned* arr, unsigned* mir, unsigned* xchk) {
  __shared__ float zred[4224];  // 4 waves x 16 rows x stride 66
  __shared__ __align__(16) f16 hstage[16][16];
  __shared__ unsigned xv[64];
  __shared__ unsigned sh_uni;
  const int tid = threadIdx.x, lane = tid & 63, w = tid >> 6;
  const int j = lane & 15, kg = lane >> 4;
  const int k0 = (int)blockIdx.x & 7, cc = (int)blockIdx.x >> 3;
  const int l = (k0 >> 2) & 1, q = k0 & 3;
  const int u0 = cc * 16, row0 = q * 16;
  const int wko = w * 256 + kg * 8;
  const int erl = tid >> 4, eunit = tid & 15;
  const int erow = row0 + erl, eu = u0 + eunit;
  unsigned* gArr = arr + (size_t)(k0 * 128) * 32;  // FIXED: 128-line stride
  unsigned* gMir = mir + (size_t)(q * 64) * 32;
  unsigned* gChk = xchk + (size_t)(k0 * 64) * 32;
  f16* myHl = (l ? Hl1 : Hl0) + (size_t)(q * 2) * 16384;  // 2 slots x 16x1024

  // ---- one-time placement check (always via L3) ----
  unsigned myxcc;
  asm volatile("s_getreg_b32 %0, hwreg(HW_REG_XCC_ID)" : "=s"(myxcc));
  if (tid == 0) st_flag(&gChk[(unsigned)cc * 32u], myxcc + 1u);
  if (tid < 64) {
    unsigned vv = 0u;
    POLL_GUARD((vv = ld_flag(&gChk[(unsigned)tid * 32u])) == 0u);
    xv[tid] = vv;
  }
  __syncthreads();
  if (tid == 0) {
    unsigned ok = 1u, v0 = xv[0];
    for (int z = 1; z < 64; ++z) ok &= (unsigned)(xv[z] == v0 && xv[z] != 0u);
    sh_uni = ok;
  }
  __syncthreads();
  const bool fast = (sh_uni != 0u);

  // resident recurrent weights (U0 for L0, U1 for L1): 4 gate-sets x 8 kt
  f16x8 bv[4][8];
  {
    const f16* RW = l ? U1t : U0t;
#pragma unroll
    for (int n = 0; n < 4; ++n) {
      const f16* bp = RW + (size_t)(n * 1024 + u0 + j) * 1024 + wko;
#pragma unroll
      for (int kt = 0; kt < 8; ++kt) bv[n][kt] = *(const f16x8*)(bp + kt * 32);
    }
  }
  float c = 0.0f;  // this thread's (row,unit) cell state

  if (l == 0) {
    // ================= layer 0 =================
    float xz[4];
#pragma unroll
    for (int g = 0; g < 4; ++g)
      xz[g] = (float)XZ[(size_t)erow * 4096 + g * 1024 + eu];

    for (int s = 0; s < 256; ++s) {
      f32x4 acc[4] = {};
      if (s > 0) {
        const f16* ap = myHl + (size_t)((s - 1) & 1) * 16384 + j * 1024 + wko;
        f16x8 av[8];
        ld_frag8(ap, fast, av);
#pragma unroll
        for (int kt = 0; kt < 8; ++kt)
#pragma unroll
          for (int n = 0; n < 4; ++n)
            acc[n] = mfma16x32(av[kt], bv[n][kt], acc[n]);
      }
#pragma unroll
      for (int n = 0; n < 4; ++n)
#pragma unroll
        for (int r = 0; r < 4; ++r)
          zred[w * 1056 + (kg * 4 + r) * 66 + n * 16 + j] = acc[n][r];
      __syncthreads();
      float z[4];
#pragma unroll
      for (int g = 0; g < 4; ++g) {
        float sm = xz[g];
#pragma unroll
        for (int wv = 0; wv < 4; ++wv)
          sm += zred[wv * 1056 + erl * 66 + g * 16 + eunit];
        z[g] = sm;
      }
      float gi = sigmoidf_(z[0]), gf = sigmoidf_(z[1]);
      float gg = tanhf(z[2]), go = sigmoidf_(z[3]);
      c = gf * c + gi * gg;
      hstage[erl][eunit] = (f16)(go * tanhf(c));
      __syncthreads();
      if (tid < 32) {
        f16x8 hv = *(const f16x8*)&hstage[tid >> 1][(tid & 1) * 8];
        // cross-XCD handoff to L1 (write-once slot, always L3)
        st_b128_sc(&A1[(size_t)(s * 64 + row0 + (tid >> 1)) * 1024 + u0 +
                       (tid & 1) * 8],
                   hv);
        // local recurrence copy (ping-pong)
        st_h16(myHl + (size_t)(s & 1) * 16384 + (tid >> 1) * 1024 + u0 +
                   (tid & 1) * 8,
               hv, fast);
      }
      asm volatile("s_waitcnt vmcnt(0)" ::: "memory");
      __syncthreads();  // all data stores committed (L2 local / L3)

      const unsigned v = (unsigned)s + 1u;
      if (tid == 0) st_flag2(&gArr[(unsigned)cc * 32u], v, fast);  // arrive
      // prefetch next xz under the barrier
      float xzn[4] = {0.f, 0.f, 0.f, 0.f};
      if (s + 1 < 256) {
        const f16* xrow = XZ + (size_t)((s + 1) * 64 + erow) * 4096;
#pragma unroll
        for (int g = 0; g < 4; ++g) xzn[g] = (float)xrow[g * 1024 + eu];
      }
      if (cc == 0) {  // leader gathers (1 reader per line)
        if (tid >= 1 && tid < 64) {
          POLL_GUARD(ld_flag2(&gArr[(unsigned)tid * 32u], fast) < v);
        }
        __syncthreads();
        if (tid >= 1 && tid < 64)
          st_flag2(&gArr[((unsigned)tid + 64u) * 32u], v, fast);  // release
      } else {
        if (tid == 0) {
          POLL_GUARD(ld_flag2(&gArr[((unsigned)cc + 64u) * 32u], fast) < v);
        }
        __syncthreads();
      }
      // publish epoch to L1's quarter (cross-XCD, 1 writer/1 reader, sc1)
      if (tid == 0) st_flag(&gMir[(unsigned)cc * 32u], v);
#pragma unroll
      for (int g = 0; g < 4; ++g) xz[g] = xzn[g];
    }
  } else {
    // ================= layer 1 =================
    float bias1[4];
#pragma unroll
    for (int g = 0; g < 4; ++g) bias1[g] = b1[g * 1024 + eu];
    const f16* w1p[4];
#pragma unroll
    for (int n = 0; n < 4; ++n)
      w1p[n] = W1t + (size_t)(n * 1024 + u0 + j) * 1024 + wko;

    // prime: wait epoch 1 (own mirror line), compute accW = W1 * h0(0)
    if (tid == 0) {
      POLL_GUARD(ld_flag(&gMir[(unsigned)cc * 32u]) < 1u);
    }
    __syncthreads();
    f32x4 accW[4] = {};
    {
      f16x8 av[8];
      ld_frag8(A1 + (size_t)(row0 + j) * 1024 + wko, false, av);  // L3 read
#pragma unroll
      for (int kt = 0; kt < 8; ++kt)
#pragma unroll
        for (int n = 0; n < 4; ++n)
          accW[n] = mfma16x32(av[kt], *(const f16x8*)(w1p[n] + kt * 32),
                              accW[n]);
    }

    for (int t = 0; t < 256; ++t) {
      f32x4 acc[4] = {accW[0], accW[1], accW[2], accW[3]};
      if (t > 0) {
        const f16* hp = myHl + (size_t)((t - 1) & 1) * 16384 + j * 1024 + wko;
        f16x8 av[8];
        ld_frag8(hp, fast, av);
#pragma unroll
        for (int kt = 0; kt < 8; ++kt)
#pragma unroll
          for (int n = 0; n < 4; ++n)
            acc[n] = mfma16x32(av[kt], bv[n][kt], acc[n]);
      }
#pragma unroll
      for (int n = 0; n < 4; ++n)
#pragma unroll
        for (int r = 0; r < 4; ++r)
          zred[w * 1056 + (kg * 4 + r) * 66 + n * 16 + j] = acc[n][r];
      __syncthreads();
      float z[4];
#pragma unroll
      for (int g = 0; g < 4; ++g) {
        float sm = bias1[g];
#pragma unroll
        for (int wv = 0; wv < 4; ++wv)
          sm += zred[wv * 1056 + erl * 66 + g * 16 + eunit];
        z[g] = sm;
      }
      float gi = sigmoidf_(z[0]), gf = sigmoidf_(z[1]);
      float gg = tanhf(z[2]), go = sigmoidf_(z[3]);
      c = gf * c + gi * gg;
      float hn = go * tanhf(c);
      if (t == 255) {
        out[(size_t)erow * 262144 + (size_t)t * 1024 + eu] = hn;
        out[16777216 + erow * 1024 + eu] = hn;
        out[16777216 + 65536 + erow * 1024 + eu] = c;
        break;  // no barrier needed after the last step
      }
      hstage[erl][eunit] = (f16)hn;
      __syncthreads();
      if (tid < 32) {
        f16x8 hv = *(const f16x8*)&hstage[tid >> 1][(tid & 1) * 8];
        st_h16(myHl + (size_t)(t & 1) * 16384 + (tid >> 1) * 1024 + u0 +
                   (tid & 1) * 8,
               hv, fast);
      }
      asm volatile("s_waitcnt vmcnt(0)" ::: "memory");
      __syncthreads();  // local h1 committed

      const unsigned v = (unsigned)t + 1u;
      if (tid == 0) st_flag2(&gArr[(unsigned)cc * 32u], v, fast);  // arrive
      // deferred out store hides under the barrier
      out[(size_t)erow * 262144 + (size_t)t * 1024 + eu] = hn;
      if (cc == 0) {
        if (tid >= 1 && tid < 64) {
          POLL_GUARD(ld_flag2(&gArr[(unsigned)tid * 32u], fast) < v);
        }
        __syncthreads();
        if (tid >= 1 && tid < 64)
          st_flag2(&gArr[((unsigned)tid + 64u) * 32u], v, fast);
      } else {
        if (tid == 0) {
          POLL_GUARD(ld_flag2(&gArr[((unsigned)cc + 64u) * 32u], fast) < v);
        }
        __syncthreads();
      }
      // overlap slot: next step's W1 pass, gated on epoch t+2 (sc1 mirror)
      if (tid == 0) {
        POLL_GUARD(ld_flag(&gMir[(unsigned)cc * 32u]) < v + 1u);
      }
      __syncthreads();
      {
        f16x8 av[8];
        ld_frag8(A1 + (size_t)((t + 1) * 64 + row0 + j) * 1024 + wko, false,
                 av);  // L3 read (write-once slot; replay-safe)
        f32x4 tw[4] = {};
#pragma unroll
        for (int kt = 0; kt < 8; ++kt)
#pragma unroll
          for (int n = 0; n < 4; ++n)
            tw[n] = mfma16x32(av[kt], *(const f16x8*)(w1p[n] + kt * 32),
                              tw[n]);
#pragma unroll
        for (int n = 0; n < 4; ++n) accW[n] = tw[n];
      }
    }
  }
}

// ---------- fallback: fused per-step kernel (r9/r10, proven) ----------
__device__ __forceinline__ void reduce4(const f32x4 acc[4], float* zred,
                                        float z[4]) {
  const int tid = threadIdx.x, lane = tid & 63, w = tid >> 6;
  const int j = lane & 15, kg = lane >> 4;
#pragma unroll
  for (int mf = 0; mf < 4; ++mf)
#pragma unroll
    for (int r = 0; r < 4; ++r)
      zred[w * 1088 + (mf * 16 + kg * 4 + r) * 17 + j] = acc[mf][r];
  __syncthreads();
  const int erow = tid >> 2, euu = tid & 3;
#pragma unroll
  for (int g = 0; g < 4; ++g) {
#pragma unroll
    for (int wv = 0; wv < 4; ++wv)
      z[g] += zred[wv * 1088 + erow * 17 + g * 4 + euu];
  }
}

__device__ __forceinline__ void step_once(
    int s, int u0, const f16x8 bvU0[8], const f16x8 bvW1[8],
    const f16x8 bvU1[8], const float bias1[4], const float xz[4],
    f16* __restrict__ A1, f16* __restrict__ H1h, int hmask,
    float& c0, float& c1, float* __restrict__ out, float* zred) {
  const int tid = threadIdx.x, lane = tid & 63, w = tid >> 6;
  const int j = lane & 15, kg = lane >> 4;
  const int aoff = j * 1024 + w * 256 + kg * 8;
  const int erow = tid >> 2;
  const int eu = u0 + (tid & 3);

  f32x4 accA[4] = {};
  f32x4 accB[4] = {};

  if (s >= 1) {
    const f16* ap = A1 + (size_t)(s - 1) * 65536 + aoff;
#pragma unroll
    for (int kt = 0; kt < 8; ++kt)
#pragma unroll
      for (int mf = 0; mf < 4; ++mf) {
        f16x8 av = *(const f16x8*)(ap + mf * 16384 + kt * 32);
        if (s < 256) accA[mf] = mfma16x32(av, bvU0[kt], accA[mf]);
        accB[mf] = mfma16x32(av, bvW1[kt], accB[mf]);
      }
    if (s >= 2) {
      const f16* hp = H1h + (size_t)((s - 2) & hmask) * 65536 + aoff;
#pragma unroll
      for (int kt = 0; kt < 8; ++kt)
#pragma unroll
        for (int mf = 0; mf < 4; ++mf)
          accB[mf] = mfma16x32(*(const f16x8*)(hp + mf * 16384 + kt * 32),
                               bvU1[kt], accB[mf]);
    }
  }

  if (s < 256) {
    float z[4] = {xz[0], xz[1], xz[2], xz[3]};
    reduce4(accA, zred, z);
    float gi = sigmoidf_(z[0]), gf = sigmoidf_(z[1]);
    float gg = tanhf(z[2]), go = sigmoidf_(z[3]);
    c0 = gf * c0 + gi * gg;
    st_f16_sc(&A1[(size_t)(s * 64 + erow) * 1024 + eu], go * tanhf(c0));
  }
  __syncthreads();

  if (s >= 1) {
    const int t = s - 1;
    float z[4] = {bias1[0], bias1[1], bias1[2], bias1[3]};
    reduce4(accB, zred, z);
    float gi = sigmoidf_(z[0]), gf = sigmoidf_(z[1]);
    float gg = tanhf(z[2]), go = sigmoidf_(z[3]);
    c1 = gf * c1 + gi * gg;
    float hn = go * tanhf(c1);
    st_f16_sc(&H1h[(size_t)(t & hmask) * 65536 + erow * 1024 + eu], hn);
    out[(size_t)erow * 262144 + (size_t)t * 1024 + eu] = hn;
    if (t == 255) {
      out[16777216 + erow * 1024 + eu] = hn;
      out[16777216 + 65536 + erow * 1024 + eu] = c1;
    }
  }
}

__global__ __launch_bounds__(256, 1) void k_step(
    const f16* __restrict__ XZ, const f16* __restrict__ U0t,
    const f16* __restrict__ W1t, const f16* __restrict__ U1t,
    const float* __restrict__ b1, f16* __restrict__ A1,
    f16* __restrict__ H1h, float* __restrict__ C0, float* __restrict__ C1,
    float* __restrict__ out, int s) {
  __shared__ float zred[4352];
  const int tid_ = threadIdx.x, lane_ = tid_ & 63, w_ = tid_ >> 6;
  const int bid_ = (int)blockIdx.x;
  const int i_ = ((bid_ & 7) << 5) + (bid_ >> 3);
  const int u0 = i_ * 4;
  const int j_ = lane_ & 15;
  const int kg_ = lane_ >> 4;
  const int ncol_ = (j_ >> 2) * 1024 + u0 + (j_ & 3);
  const int woff_ = ncol_ * 1024 + w_ * 256 + kg_ * 8;
  f16x8 bvU0[8], bvW1[8], bvU1[8];
#pragma unroll
  for (int kt = 0; kt < 8; ++kt) {
    bvU0[kt] = *(const f16x8*)(U0t + woff_ + kt * 32);
    bvW1[kt] = *(const f16x8*)(W1t + woff_ + kt * 32);
    bvU1[kt] = *(const f16x8*)(U1t + woff_ + kt * 32);
  }
  const int erow_ = tid_ >> 2;
  const int eu_ = u0 + (tid_ & 3);
  float bias1[4];
#pragma unroll
  for (int g = 0; g < 4; ++g) bias1[g] = b1[g * 1024 + eu_];

  float xz[4] = {0.f, 0.f, 0.f, 0.f};
  if (s < 256) {
    const f16* xrow = XZ + (size_t)(s * 64 + erow_) * 4096;
#pragma unroll
    for (int g = 0; g < 4; ++g) xz[g] = (float)xrow[g * 1024 + eu_];
  }
  float c0 = C0[erow_ * 1024 + eu_];
  float c1 = C1[erow_ * 1024 + eu_];
  step_once(s, u0, bvU0, bvW1, bvU1, bias1, xz, A1, H1h, 1, c0, c1, out,
            zred);
  C0[erow_ * 1024 + eu_] = c0;
  C1[erow_ * 1024 + eu_] = c1;
}

extern "C" void kernel_launch(void* const* d_in, const int* in_sizes, int n_in,
                              void* d_out, int out_size, void* d_ws, size_t ws_size,
                              hipStream_t stream) {
  (void)in_sizes; (void)n_in; (void)out_size;
  const int* tokens = (const int*)d_in[0];
  const float* emb = (const float*)d_in[1];
  const float* W0 = (const float*)d_in[2];
  const float* U0 = (const float*)d_in[3];
  const float* b0 = (const float*)d_in[4];
  const float* W1 = (const float*)d_in[5];
  const float* U1 = (const float*)d_in[6];
  const float* b1 = (const float*)d_in[7];
  float* out = (float*)d_out;

  // workspace carve-up
  char* p = (char*)d_ws;
  f16* A0 = (f16*)p;   p += (size_t)16384 * 512 * 2;    // x tokens, fp16
  f16* A1 = (f16*)p;   p += (size_t)16384 * 1024 * 2;   // h0 history
  f16* W0t = (f16*)p;  p += (size_t)4096 * 512 * 2;     // W0^T
  f16* U0t = (f16*)p;  p += (size_t)4096 * 1024 * 2;    // U0^T
  f16* W1t = (f16*)p;  p += (size_t)4096 * 1024 * 2;    // W1^T
  f16* U1t = (f16*)p;  p += (size_t)4096 * 1024 * 2;    // U1^T
  f16* XZ = (f16*)p;   p += (size_t)16384 * 4096 * 2;   // xz0, rows t*64+b
  float* C0 = (float*)p; p += 64 * 1024 * 4;            // cell L0 (fallback)
  float* C1 = (float*)p; p += 64 * 1024 * 4;            // cell L1 (fallback)
  unsigned* arr = (unsigned*)p; p += 8 * 128 * 32 * 4;  // arrive+release
  unsigned* mir = (unsigned*)p; p += 4 * 64 * 32 * 4;   // epoch mirrors
  unsigned* xchk = (unsigned*)p; p += 8 * 64 * 32 * 4;  // placement check
  f16* Hl0 = (f16*)p;  p += (size_t)4 * 2 * 16384 * 2;  // L0 local h pingpong
  f16* Hl1 = (f16*)p;  p += (size_t)4 * 2 * 16384 * 2;  // L1 local h pingpong
  f16* H1h = (f16*)p;  p += (size_t)2 * 65536 * 2;      // fallback h1 pingpong
  const size_t need_coop = (size_t)(p - (char*)d_ws);

  // weight transposes + casts
  k_transpose_f16<<<512, 256, 0, stream>>>(W0, W0t, 512, 4096);
  k_transpose_f16<<<1024, 256, 0, stream>>>(U0, U0t, 1024, 4096);
  k_transpose_f16<<<1024, 256, 0, stream>>>(W1, W1t, 1024, 4096);
  k_transpose_f16<<<1024, 256, 0, stream>>>(U1, U1t, 1024, 4096);

  // embedding
  k_embed_f16<<<8192, 256, 0, stream>>>(tokens, emb, A0);

  // layer 0 input projection: xz0 = x @ W0 + b0
  k_gemm_f16<<<4096, 256, 0, stream>>>(A0, W0t, b0, XZ, 16384, 4096, 512);

  hipMemsetAsync(C0, 0, 64 * 1024 * 4 * 2, stream);  // C0+C1
  hipMemsetAsync(arr, 0, (8 * 128 + 4 * 64 + 8 * 64) * 32 * 4, stream);

  bool coop_ok = (ws_size >= need_coop);
  if (coop_ok) {
    const f16* XZc = XZ; const f16* U0c = U0t; const f16* W1c = W1t;
    const f16* U1c = U1t; const float* b1c = b1;
    f16* A1p = A1; f16* Hl0p = Hl0; f16* Hl1p = Hl1; float* outp = out;
    unsigned* ar = arr; unsigned* mr = mir; unsigned* xc = xchk;
    void* kargs[] = {(void*)&XZc, (void*)&U0c, (void*)&W1c, (void*)&U1c,
                     (void*)&b1c, (void*)&A1p, (void*)&Hl0p, (void*)&Hl1p,
                     (void*)&outp, (void*)&ar, (void*)&mr, (void*)&xc};
    hipError_t e = hipLaunchCooperativeKernel((const void*)k_scanA, dim3(512),
                                              dim3(256), kargs, 0, stream);
    if (e != hipSuccess) {
      (void)hipGetLastError();
      coop_ok = false;
    }
  }
  if (!coop_ok) {
    for (int s = 0; s <= 256; ++s)
      k_step<<<256, 256, 0, stream>>>(XZ, U0t, W1t, U1t, b1, A1, H1h, C0, C1,
                                      out, s);
  }
}

// Round 17
// 2659.288 us; speedup vs baseline: 3386.6405x; 3386.6405x over previous
//
#include <hip/hip_runtime.h>

// LSTM encoder: V=32000 E=512 U=1024 L=2, B=64 T=256.
// Round 17: r14's decomposition (8 groups of 64 blocks = layer x batch
// quarter; 64-col blocks, 1 A-frag x 4 resident B-frags, coalesced sc0sc1
// h stores) + r13's PROVEN leader-gather two-hop barrier (1 reader/line).
// r14's all-observe barrier (64 pollers/line at L3) was its regression;
// r15/r16's XCD-local cache protocol is abandoned (visibility only via
// eviction -> 9s). L0->L1 epoch via 1-writer/1-reader mirror lines written
// by the L0 leader after its gather (r13 pattern). POLL_GUARD retained.

typedef _Float16 f16;
typedef _Float16 f16x8 __attribute__((ext_vector_type(8)));
typedef _Float16 f16x4 __attribute__((ext_vector_type(4)));
typedef float f32x4 __attribute__((ext_vector_type(4)));

#define POLL_GUARD(cond)                                     \
  {                                                          \
    unsigned gg_ = 0;                                        \
    while ((cond) && (++gg_ < (1u << 18)))                   \
      __builtin_amdgcn_s_sleep(1);                           \
  }

__device__ __forceinline__ f32x4 mfma16x32(f16x8 a, f16x8 b, f32x4 c) {
  return __builtin_amdgcn_mfma_f32_16x16x32_f16(a, b, c, 0, 0, 0);
}

__device__ __forceinline__ void gl_lds16(const void* g, void* l) {
  __builtin_amdgcn_global_load_lds(
      (const __attribute__((address_space(1))) void*)g,
      (__attribute__((address_space(3))) void*)l, 16, 0, 0);
}

__device__ __forceinline__ float sigmoidf_(float x) {
  return 1.0f / (1.0f + expf(-x));
}

// write-through stores: land at the L3 coherence point, no dirty L2 line
__device__ __forceinline__ void st_f16_sc(f16* p, float v) {
  f16 h = (f16)v;
  unsigned u = (unsigned)__builtin_bit_cast(unsigned short, h);
  asm volatile("global_store_short %0, %1, off sc0 sc1"
               :: "v"(p), "v"(u) : "memory");
}
__device__ __forceinline__ void st_b128_sc(f16* p, f16x8 v) {
  asm volatile("global_store_dwordx4 %0, %1, off sc0 sc1"
               :: "v"(p), "v"(v) : "memory");
}

// L3 (agent) flags: 1-writer/1-reader lines, relaxed (proven r5-r13)
__device__ __forceinline__ unsigned ld_flag(const unsigned* p) {
  return __hip_atomic_load(p, __ATOMIC_RELAXED, __HIP_MEMORY_SCOPE_AGENT);
}
__device__ __forceinline__ void st_flag(unsigned* p, unsigned v) {
  __hip_atomic_store(p, v, __ATOMIC_RELAXED, __HIP_MEMORY_SCOPE_AGENT);
}

// ---------- transpose + cast: D[n][k] = (f16)S[k][n] ----------
__global__ __launch_bounds__(256) void k_transpose_f16(
    const float* __restrict__ S, f16* __restrict__ D, int K, int N) {
  __shared__ float tile[64][65];
  int nk = K >> 6;
  int k0 = (blockIdx.x % nk) << 6;
  int n0 = (blockIdx.x / nk) << 6;
  int tc = threadIdx.x & 63;
  int tq = threadIdx.x >> 6;
#pragma unroll
  for (int r = 0; r < 16; ++r) {
    int kk = tq * 16 + r;
    tile[kk][tc] = S[(size_t)(k0 + kk) * N + (n0 + tc)];
  }
  __syncthreads();
#pragma unroll
  for (int r = 0; r < 16; ++r) {
    int nn = tq * 16 + r;
    D[(size_t)(n0 + nn) * K + (k0 + tc)] = (f16)tile[tc][nn];
  }
}

// ---------- embedding lookup -> fp16 A0[m][512], row m = t*64 + b ----------
__global__ __launch_bounds__(256) void k_embed_f16(
    const int* __restrict__ tok, const float* __restrict__ emb,
    f16* __restrict__ A0) {
  int i = blockIdx.x * 256 + threadIdx.x;
  int m = i >> 7;
  int e = (i & 127) << 2;
  int t = m >> 6, b = m & 63;
  int tk = tok[b * 256 + t];
  const float4 v = *(const float4*)(emb + (size_t)tk * 512 + e);
  f16x4 o = {(f16)v.x, (f16)v.y, (f16)v.z, (f16)v.w};
  *(f16x4*)(A0 + (size_t)m * 512 + e) = o;
}

// ---------- C[m][n] = (f16)(sum_k A[m][k]*Bt[n][k] + bias[n]) ----------
__global__ __launch_bounds__(256) void k_gemm_f16(
    const f16* __restrict__ A, const f16* __restrict__ Bt,
    const float* __restrict__ bias, f16* __restrict__ C,
    int M, int N, int K) {
  __shared__ f16 sA[2][128 * 32];
  __shared__ f16 sB[2][128 * 32];
  const int tid = threadIdx.x, lane = tid & 63, w = tid >> 6;
  const int mb = M >> 7;
  const int bm = blockIdx.x % mb, bn = blockIdx.x / mb;
  const int am0 = bm << 7, bn0 = bn << 7;
  const int wm = w >> 1, wn = w & 1;
  const int srow = lane >> 2, sch = lane & 3;

  f32x4 acc[4][4] = {};
  const int NT = K >> 5;
  int cur = 0;

  auto stage = [&](int kt, int buf) {
#pragma unroll
    for (int q2 = 0; q2 < 2; ++q2) {
      int q = w * 2 + q2;
      int row = q * 16 + srow;
      const f16* ga = A + (size_t)(am0 + row) * K + kt * 32 + sch * 8;
      const f16* gb = Bt + (size_t)(bn0 + row) * K + kt * 32 + sch * 8;
      gl_lds16(ga, (char*)&sA[buf][0] + q * 1024);
      gl_lds16(gb, (char*)&sB[buf][0] + q * 1024);
    }
  };

  stage(0, 0);
  __syncthreads();
  for (int kt = 0; kt < NT; ++kt) {
    if (kt + 1 < NT) stage(kt + 1, cur ^ 1);
    const f16* pa = &sA[cur][(wm * 64 + (lane & 15)) * 32 + (lane >> 4) * 8];
    const f16* pb = &sB[cur][(wn * 64 + (lane & 15)) * 32 + (lane >> 4) * 8];
    f16x8 av[4], bv[4];
#pragma unroll
    for (int mf = 0; mf < 4; ++mf) av[mf] = *(const f16x8*)(pa + mf * 512);
#pragma unroll
    for (int nf = 0; nf < 4; ++nf) bv[nf] = *(const f16x8*)(pb + nf * 512);
#pragma unroll
    for (int mf = 0; mf < 4; ++mf)
#pragma unroll
      for (int nf = 0; nf < 4; ++nf)
        acc[mf][nf] = mfma16x32(av[mf], bv[nf], acc[mf][nf]);
    __syncthreads();
    cur ^= 1;
  }

#pragma unroll
  for (int mf = 0; mf < 4; ++mf)
#pragma unroll
    for (int nf = 0; nf < 4; ++nf) {
      int col = bn0 + wn * 64 + nf * 16 + (lane & 15);
      float bs = bias[col];
#pragma unroll
      for (int r = 0; r < 4; ++r) {
        int row = am0 + wm * 64 + mf * 16 + (lane >> 4) * 4 + r;
        C[(size_t)row * N + col] = (f16)(acc[mf][nf][r] + bs);
      }
    }
}

// ---------- quarter-group scan, leader-gather barrier ----------
// 512 blocks x 256 thr. l = bid>>8 (layer), rb = bid&255, q = rb>>6
// (batch quarter: rows q*16..q*16+16), i = rb&63 (group id),
// cc = (i&7)*8 + i>>3 (col chunk, XCD-local), units [cc*16,cc*16+16) x 4
// gates = 64 cols/block. Group (l,q): 64 blocks; flag region 128 lines
// (arrive i / release 64+i). Epoch: L0 leader writes mir[q][i] (1 writer /
// 1 reader) after gather; L1 block i polls its own line.
__global__ __launch_bounds__(256, 2) void k_scanB(
    const f16* __restrict__ XZ, const f16* __restrict__ U0t,
    const f16* __restrict__ W1t, const f16* __restrict__ U1t,
    const float* __restrict__ b1, f16* __restrict__ A1,
    f16* __restrict__ H1h, float* __restrict__ out, unsigned* arr,
    unsigned* mir) {
  __shared__ float zred[4224];  // 4 waves x 16 rows x stride 66
  __shared__ __align__(16) f16 hstage[16][16];
  const int tid = threadIdx.x, lane = tid & 63, w = tid >> 6;
  const int j = lane & 15, kg = lane >> 4;
  const int l = (int)blockIdx.x >> 8;
  const int rb = (int)blockIdx.x & 255;
  const int q = rb >> 6, i = rb & 63;
  const int cc = ((i & 7) << 3) + (i >> 3);
  const int u0 = cc * 16, row0 = q * 16;
  const int wko = w * 256 + kg * 8;
  const int aoff = (row0 + j) * 1024 + wko;
  const int erl = tid >> 4, eunit = tid & 15;
  const int erow = row0 + erl, eu = u0 + eunit;
  unsigned* gArr = arr + (size_t)((l * 4 + q) * 128) * 32;
  unsigned* gMir = mir + (size_t)(q * 64) * 32;

  // resident recurrent weights (U0 for L0, U1 for L1): 4 gate-sets x 8 kt
  f16x8 bv[4][8];
  {
    const f16* RW = l ? U1t : U0t;
#pragma unroll
    for (int n = 0; n < 4; ++n) {
      const f16* bp = RW + (size_t)(n * 1024 + u0 + j) * 1024 + wko;
#pragma unroll
      for (int kt = 0; kt < 8; ++kt)
        bv[n][kt] = *(const f16x8*)(bp + kt * 32);
    }
  }
  float c = 0.0f;  // this thread's (row,unit) cell state

  if (l == 0) {
    // ================= layer 0 =================
    float xz[4];
#pragma unroll
    for (int g = 0; g < 4; ++g)
      xz[g] = (float)XZ[(size_t)erow * 4096 + g * 1024 + eu];

    for (int s = 0; s < 256; ++s) {
      f32x4 acc[4] = {};
      if (s > 0) {
        const f16* ap = A1 + (size_t)(s - 1) * 65536 + aoff;
#pragma unroll
        for (int kt = 0; kt < 8; ++kt) {
          f16x8 av = *(const f16x8*)(ap + kt * 32);
#pragma unroll
          for (int n = 0; n < 4; ++n)
            acc[n] = mfma16x32(av, bv[n][kt], acc[n]);
        }
      }
#pragma unroll
      for (int n = 0; n < 4; ++n)
#pragma unroll
        for (int r = 0; r < 4; ++r)
          zred[w * 1056 + (kg * 4 + r) * 66 + n * 16 + j] = acc[n][r];
      __syncthreads();
      float z[4];
#pragma unroll
      for (int g = 0; g < 4; ++g) {
        float sm = xz[g];
#pragma unroll
        for (int wv = 0; wv < 4; ++wv)
          sm += zred[wv * 1056 + erl * 66 + g * 16 + eunit];
        z[g] = sm;
      }
      float gi = sigmoidf_(z[0]), gf = sigmoidf_(z[1]);
      float gg = tanhf(z[2]), go = sigmoidf_(z[3]);
      c = gf * c + gi * gg;
      hstage[erl][eunit] = (f16)(go * tanhf(c));
      __syncthreads();
      if (tid < 32)
        st_b128_sc(&A1[(size_t)(s * 64 + row0 + (tid >> 1)) * 1024 + u0 +
                       (tid & 1) * 8],
                   *(const f16x8*)&hstage[tid >> 1][(tid & 1) * 8]);
      asm volatile("s_waitcnt vmcnt(0)" ::: "memory");
      __syncthreads();  // h stores at L3

      const unsigned v = (unsigned)s + 1u;
      if (tid == 0) st_flag(&gArr[(unsigned)i * 32u], v);  // arrive
      // prefetch next xz under the barrier
      float xzn[4] = {0.f, 0.f, 0.f, 0.f};
      if (s + 1 < 256) {
        const f16* xrow = XZ + (size_t)((s + 1) * 64 + erow) * 4096;
#pragma unroll
        for (int g = 0; g < 4; ++g) xzn[g] = (float)xrow[g * 1024 + eu];
      }
      if (i == 0) {  // leader: gather (1 reader/line), release, epoch
        if (tid >= 1 && tid < 64) {
          POLL_GUARD(ld_flag(&gArr[(unsigned)tid * 32u]) < v);
        }
        __syncthreads();
        if (tid >= 1 && tid < 64)
          st_flag(&gArr[((unsigned)tid + 64u) * 32u], v);  // release
        if (tid < 64) st_flag(&gMir[(unsigned)tid * 32u], v);  // epoch
      } else {
        if (tid == 0) {
          POLL_GUARD(ld_flag(&gArr[((unsigned)i + 64u) * 32u]) < v);
        }
        __syncthreads();
      }
#pragma unroll
      for (int g = 0; g < 4; ++g) xz[g] = xzn[g];
    }
  } else {
    // ================= layer 1 =================
    float bias1[4];
#pragma unroll
    for (int g = 0; g < 4; ++g) bias1[g] = b1[g * 1024 + eu];
    const f16* w1p[4];
#pragma unroll
    for (int n = 0; n < 4; ++n)
      w1p[n] = W1t + (size_t)(n * 1024 + u0 + j) * 1024 + wko;

    // prime: wait epoch 1 (own mirror line), compute accW = W1 * h0(0)
    if (tid == 0) {
      POLL_GUARD(ld_flag(&gMir[(unsigned)i * 32u]) < 1u);
    }
    __syncthreads();
    f32x4 accW[4] = {};
    {
      const f16* ap = A1 + aoff;
#pragma unroll
      for (int kt = 0; kt < 8; ++kt) {
        f16x8 av = *(const f16x8*)(ap + kt * 32);
#pragma unroll
        for (int n = 0; n < 4; ++n)
          accW[n] = mfma16x32(av, *(const f16x8*)(w1p[n] + kt * 32),
                              accW[n]);
      }
    }

    for (int t = 0; t < 256; ++t) {
      f32x4 acc[4] = {accW[0], accW[1], accW[2], accW[3]};
      if (t > 0) {
        const f16* hp = H1h + (size_t)(t - 1) * 65536 + aoff;
#pragma unroll
        for (int kt = 0; kt < 8; ++kt) {
          f16x8 av = *(const f16x8*)(hp + kt * 32);
#pragma unroll
          for (int n = 0; n < 4; ++n)
            acc[n] = mfma16x32(av, bv[n][kt], acc[n]);
        }
      }
#pragma unroll
      for (int n = 0; n < 4; ++n)
#pragma unroll
        for (int r = 0; r < 4; ++r)
          zred[w * 1056 + (kg * 4 + r) * 66 + n * 16 + j] = acc[n][r];
      __syncthreads();
      float z[4];
#pragma unroll
      for (int g = 0; g < 4; ++g) {
        float sm = bias1[g];
#pragma unroll
        for (int wv = 0; wv < 4; ++wv)
          sm += zred[wv * 1056 + erl * 66 + g * 16 + eunit];
        z[g] = sm;
      }
      float gi = sigmoidf_(z[0]), gf = sigmoidf_(z[1]);
      float gg = tanhf(z[2]), go = sigmoidf_(z[3]);
      c = gf * c + gi * gg;
      float hn = go * tanhf(c);
      if (t == 255) {
        out[(size_t)erow * 262144 + (size_t)t * 1024 + eu] = hn;
        out[16777216 + erow * 1024 + eu] = hn;
        out[16777216 + 65536 + erow * 1024 + eu] = c;
        break;  // last step: no publish/barrier needed
      }
      hstage[erl][eunit] = (f16)hn;
      __syncthreads();
      if (tid < 32)
        st_b128_sc(&H1h[(size_t)t * 65536 + (row0 + (tid >> 1)) * 1024 + u0 +
                        (tid & 1) * 8],
                   *(const f16x8*)&hstage[tid >> 1][(tid & 1) * 8]);
      asm volatile("s_waitcnt vmcnt(0)" ::: "memory");
      __syncthreads();  // h stores at L3

      const unsigned v = (unsigned)t + 1u;
      if (tid == 0) st_flag(&gArr[(unsigned)i * 32u], v);  // arrive
      // deferred out store hides under the barrier
      out[(size_t)erow * 262144 + (size_t)t * 1024 + eu] = hn;
      if (i == 0) {
        if (tid >= 1 && tid < 64) {
          POLL_GUARD(ld_flag(&gArr[(unsigned)tid * 32u]) < v);
        }
        __syncthreads();
        if (tid >= 1 && tid < 64)
          st_flag(&gArr[((unsigned)tid + 64u) * 32u], v);
      } else {
        if (tid == 0) {
          POLL_GUARD(ld_flag(&gArr[((unsigned)i + 64u) * 32u]) < v);
        }
        __syncthreads();
      }
      // overlap: next step's W1 pass, gated on epoch t+2 (own mirror line)
      if (tid == 0) {
        POLL_GUARD(ld_flag(&gMir[(unsigned)i * 32u]) < v + 1u);
      }
      __syncthreads();
      {
        const f16* ap = A1 + (size_t)(t + 1) * 65536 + aoff;
        f32x4 tw[4] = {};
#pragma unroll
        for (int kt = 0; kt < 8; ++kt) {
          f16x8 av = *(const f16x8*)(ap + kt * 32);
#pragma unroll
          for (int n = 0; n < 4; ++n)
            tw[n] = mfma16x32(av, *(const f16x8*)(w1p[n] + kt * 32), tw[n]);
        }
#pragma unroll
        for (int n = 0; n < 4; ++n) accW[n] = tw[n];
      }
    }
  }
}

// ---------- fallback: fused per-step kernel (r9/r10, proven) ----------
__device__ __forceinline__ void reduce4(const f32x4 acc[4], float* zred,
                                        float z[4]) {
  const int tid = threadIdx.x, lane = tid & 63, w = tid >> 6;
  const int j = lane & 15, kg = lane >> 4;
#pragma unroll
  for (int mf = 0; mf < 4; ++mf)
#pragma unroll
    for (int r = 0; r < 4; ++r)
      zred[w * 1088 + (mf * 16 + kg * 4 + r) * 17 + j] = acc[mf][r];
  __syncthreads();
  const int erow = tid >> 2, euu = tid & 3;
#pragma unroll
  for (int g = 0; g < 4; ++g) {
#pragma unroll
    for (int wv = 0; wv < 4; ++wv)
      z[g] += zred[wv * 1088 + erow * 17 + g * 4 + euu];
  }
}

__device__ __forceinline__ void step_once(
    int s, int u0, const f16x8 bvU0[8], const f16x8 bvW1[8],
    const f16x8 bvU1[8], const float bias1[4], const float xz[4],
    f16* __restrict__ A1, f16* __restrict__ H1h, int hmask,
    float& c0, float& c1, float* __restrict__ out, float* zred) {
  const int tid = threadIdx.x, lane = tid & 63, w = tid >> 6;
  const int j = lane & 15, kg = lane >> 4;
  const int aoff = j * 1024 + w * 256 + kg * 8;
  const int erow = tid >> 2;
  const int eu = u0 + (tid & 3);

  f32x4 accA[4] = {};
  f32x4 accB[4] = {};

  if (s >= 1) {
    const f16* ap = A1 + (size_t)(s - 1) * 65536 + aoff;
#pragma unroll
    for (int kt = 0; kt < 8; ++kt)
#pragma unroll
      for (int mf = 0; mf < 4; ++mf) {
        f16x8 av = *(const f16x8*)(ap + mf * 16384 + kt * 32);
        if (s < 256) accA[mf] = mfma16x32(av, bvU0[kt], accA[mf]);
        accB[mf] = mfma16x32(av, bvW1[kt], accB[mf]);
      }
    if (s >= 2) {
      const f16* hp = H1h + (size_t)((s - 2) & hmask) * 65536 + aoff;
#pragma unroll
      for (int kt = 0; kt < 8; ++kt)
#pragma unroll
        for (int mf = 0; mf < 4; ++mf)
          accB[mf] = mfma16x32(*(const f16x8*)(hp + mf * 16384 + kt * 32),
                               bvU1[kt], accB[mf]);
    }
  }

  if (s < 256) {
    float z[4] = {xz[0], xz[1], xz[2], xz[3]};
    reduce4(accA, zred, z);
    float gi = sigmoidf_(z[0]), gf = sigmoidf_(z[1]);
    float gg = tanhf(z[2]), go = sigmoidf_(z[3]);
    c0 = gf * c0 + gi * gg;
    st_f16_sc(&A1[(size_t)(s * 64 + erow) * 1024 + eu], go * tanhf(c0));
  }
  __syncthreads();

  if (s >= 1) {
    const int t = s - 1;
    float z[4] = {bias1[0], bias1[1], bias1[2], bias1[3]};
    reduce4(accB, zred, z);
    float gi = sigmoidf_(z[0]), gf = sigmoidf_(z[1]);
    float gg = tanhf(z[2]), go = sigmoidf_(z[3]);
    c1 = gf * c1 + gi * gg;
    float hn = go * tanhf(c1);
    st_f16_sc(&H1h[(size_t)(t & hmask) * 65536 + erow * 1024 + eu], hn);
    out[(size_t)erow * 262144 + (size_t)t * 1024 + eu] = hn;
    if (t == 255) {
      out[16777216 + erow * 1024 + eu] = hn;
      out[16777216 + 65536 + erow * 1024 + eu] = c1;
    }
  }
}

__global__ __launch_bounds__(256, 1) void k_step(
    const f16* __restrict__ XZ, const f16* __restrict__ U0t,
    const f16* __restrict__ W1t, const f16* __restrict__ U1t,
    const float* __restrict__ b1, f16* __restrict__ A1,
    f16* __restrict__ H1h, float* __restrict__ C0, float* __restrict__ C1,
    float* __restrict__ out, int s) {
  __shared__ float zred[4352];
  const int tid_ = threadIdx.x, lane_ = tid_ & 63, w_ = tid_ >> 6;
  const int bid_ = (int)blockIdx.x;
  const int i_ = ((bid_ & 7) << 5) + (bid_ >> 3);
  const int u0 = i_ * 4;
  const int j_ = lane_ & 15;
  const int kg_ = lane_ >> 4;
  const int ncol_ = (j_ >> 2) * 1024 + u0 + (j_ & 3);
  const int woff_ = ncol_ * 1024 + w_ * 256 + kg_ * 8;
  f16x8 bvU0[8], bvW1[8], bvU1[8];
#pragma unroll
  for (int kt = 0; kt < 8; ++kt) {
    bvU0[kt] = *(const f16x8*)(U0t + woff_ + kt * 32);
    bvW1[kt] = *(const f16x8*)(W1t + woff_ + kt * 32);
    bvU1[kt] = *(const f16x8*)(U1t + woff_ + kt * 32);
  }
  const int erow_ = tid_ >> 2;
  const int eu_ = u0 + (tid_ & 3);
  float bias1[4];
#pragma unroll
  for (int g = 0; g < 4; ++g) bias1[g] = b1[g * 1024 + eu_];

  float xz[4] = {0.f, 0.f, 0.f, 0.f};
  if (s < 256) {
    const f16* xrow = XZ + (size_t)(s * 64 + erow_) * 4096;
#pragma unroll
    for (int g = 0; g < 4; ++g) xz[g] = (float)xrow[g * 1024 + eu_];
  }
  float c0 = C0[erow_ * 1024 + eu_];
  float c1 = C1[erow_ * 1024 + eu_];
  step_once(s, u0, bvU0, bvW1, bvU1, bias1, xz, A1, H1h, 1, c0, c1, out,
            zred);
  C0[erow_ * 1024 + eu_] = c0;
  C1[erow_ * 1024 + eu_] = c1;
}

extern "C" void kernel_launch(void* const* d_in, const int* in_sizes, int n_in,
                              void* d_out, int out_size, void* d_ws, size_t ws_size,
                              hipStream_t stream) {
  (void)in_sizes; (void)n_in; (void)out_size;
  const int* tokens = (const int*)d_in[0];
  const float* emb = (const float*)d_in[1];
  const float* W0 = (const float*)d_in[2];
  const float* U0 = (const float*)d_in[3];
  const float* b0 = (const float*)d_in[4];
  const float* W1 = (const float*)d_in[5];
  const float* U1 = (const float*)d_in[6];
  const float* b1 = (const float*)d_in[7];
  float* out = (float*)d_out;

  // workspace carve-up; H1h LAST (coop path needs the full 256 slots)
  char* p = (char*)d_ws;
  f16* A0 = (f16*)p;   p += (size_t)16384 * 512 * 2;    // x tokens, fp16
  f16* A1 = (f16*)p;   p += (size_t)16384 * 1024 * 2;   // h0 history
  f16* W0t = (f16*)p;  p += (size_t)4096 * 512 * 2;     // W0^T
  f16* U0t = (f16*)p;  p += (size_t)4096 * 1024 * 2;    // U0^T
  f16* W1t = (f16*)p;  p += (size_t)4096 * 1024 * 2;    // W1^T
  f16* U1t = (f16*)p;  p += (size_t)4096 * 1024 * 2;    // U1^T
  f16* XZ = (f16*)p;   p += (size_t)16384 * 4096 * 2;   // xz0, rows t*64+b
  float* C0 = (float*)p; p += 64 * 1024 * 4;            // cell L0 (fallback)
  float* C1 = (float*)p; p += 64 * 1024 * 4;            // cell L1 (fallback)
  unsigned* arr = (unsigned*)p; p += 8 * 128 * 32 * 4;  // arrive+release
  unsigned* mir = (unsigned*)p; p += 4 * 64 * 32 * 4;   // epoch mirrors
  f16* H1h = (f16*)p;                                   // h1 history slots
  const size_t need_coop = (size_t)(p - (char*)d_ws) + (size_t)256 * 65536 * 2;

  // weight transposes + casts
  k_transpose_f16<<<512, 256, 0, stream>>>(W0, W0t, 512, 4096);
  k_transpose_f16<<<1024, 256, 0, stream>>>(U0, U0t, 1024, 4096);
  k_transpose_f16<<<1024, 256, 0, stream>>>(W1, W1t, 1024, 4096);
  k_transpose_f16<<<1024, 256, 0, stream>>>(U1, U1t, 1024, 4096);

  // embedding
  k_embed_f16<<<8192, 256, 0, stream>>>(tokens, emb, A0);

  // layer 0 input projection: xz0 = x @ W0 + b0
  k_gemm_f16<<<4096, 256, 0, stream>>>(A0, W0t, b0, XZ, 16384, 4096, 512);

  hipMemsetAsync(C0, 0, 64 * 1024 * 4 * 2, stream);            // C0+C1
  hipMemsetAsync(arr, 0, (8 * 128 + 4 * 64) * 32 * 4, stream); // arr+mir

  bool coop_ok = (ws_size >= need_coop);
  if (coop_ok) {
    const f16* XZc = XZ; const f16* U0c = U0t; const f16* W1c = W1t;
    const f16* U1c = U1t; const float* b1c = b1;
    f16* A1p = A1; f16* H1p = H1h; float* outp = out;
    unsigned* ar = arr; unsigned* mr = mir;
    void* kargs[] = {(void*)&XZc, (void*)&U0c, (void*)&W1c, (void*)&U1c,
                     (void*)&b1c, (void*)&A1p, (void*)&H1p, (void*)&outp,
                     (void*)&ar, (void*)&mr};
    hipError_t e = hipLaunchCooperativeKernel((const void*)k_scanB, dim3(512),
                                              dim3(256), kargs, 0, stream);
    if (e != hipSuccess) {
      (void)hipGetLastError();
      coop_ok = false;
    }
  }
  if (!coop_ok) {
    for (int s = 0; s <= 256; ++s)
      k_step<<<256, 256, 0, stream>>>(XZ, U0t, W1t, U1t, b1, A1, H1h, C0, C1,
                                      out, s);
  }
}